// Round 4
// baseline (85520.325 us; speedup 1.0000x reference)
//
#include <hip/hip_runtime.h>
#include <hip/hip_cooperative_groups.h>
#include <math.h>

namespace cg = cooperative_groups;

#define SZ 300
#define TS 64
#define B_ 512
#define NS 128
#define TT 255
#define G4 256
#define R5 1500

#define NBLK 256
#define NTHR 512
#define RPB 16            // batch rows per row-group
#define PANSZ 8640        // panel buffer floats per buffer (20*432 max)

__device__ __forceinline__ float sigf(float x){ return 1.f/(1.f+expf(-x)); }

// ---------------------------------------------------------------------------
// Schedule precompute: codes: >=0 token idx; -1 zero; <=-2 stack slot (-c-2)
// ---------------------------------------------------------------------------
__global__ void kSched(const int* __restrict__ trans, int* __restrict__ src1,
                       int* __restrict__ src2, int* __restrict__ bsrcA,
                       int* __restrict__ sspA, int* __restrict__ finCode)
{
    int b = blockIdx.x * blockDim.x + threadIdx.x;
    if (b >= B_) return;
    int arr[NS];
    int sp = 0, bp = 0;
    for (int t = 0; t < TT; ++t) {
        sspA [t*B_+b] = sp;
        bsrcA[t*B_+b] = min(bp, NS-1);
        src1 [t*B_+b] = (sp >= 1) ? arr[sp-1] : -1;
        src2 [t*B_+b] = (sp >= 2) ? arr[sp-2] : -1;
        if (trans[b*TT + t]) { arr[sp-2] = -(sp-2)-2; sp -= 1; }
        else { if (sp < NS) arr[sp] = min(bp, NS-1); sp += 1; bp += 1; }
    }
    finCode[b] = (sp >= 1) ? arr[sp-1] : -1;
}

// ---------------------------------------------------------------------------
// Persistent cooperative SPINN kernel.
// 256 blocks = 32 row-groups (16 rows) x 8 slices. 512 threads.
// slice 0: x-slice + tracking LSTM/logits; slices 1-7: x-slice + r-GEMM
// (43/43/43/43/43/43/42 tree-cols x 5 gates) + tree pointwise + stack write.
// Weights stream L2->LDS panels (double-buffered); A lives in LDS per block.
// 3 grid.sync() per step.
// ---------------------------------------------------------------------------
__global__ __launch_bounds__(NTHR, 2) void kSpinn(
    const float* __restrict__ tokens, const float* __restrict__ Wb,
    const float* __restrict__ Ws1, const float* __restrict__ Ws2,
    const float* __restrict__ W_ih, const float* __restrict__ W_hh,
    const float* __restrict__ Wt, const float* __restrict__ bt,
    const float* __restrict__ WL, const float* __restrict__ WR,
    const float* __restrict__ Wtr, const float* __restrict__ bL,
    const int* __restrict__ trans, const int* __restrict__ src1,
    const int* __restrict__ src2, const int* __restrict__ bsrcA,
    const int* __restrict__ sspA, const int* __restrict__ finCode,
    float* __restrict__ stack, float* __restrict__ xBuf,
    float* __restrict__ thBuf, float* __restrict__ nllBuf,
    float* __restrict__ out)
{
    __shared__ __align__(16) float bigA[RPB*900];        // 57.6 KB (overlaid)
    __shared__ __align__(16) float panelBuf[2*PANSZ];    // 69.1 KB
    __shared__ __align__(16) float sTh[RPB][TS];
    __shared__ __align__(16) float sTc[RPB][TS];
    __shared__ int   vtab[432];
    __shared__ int   sC1[RPB], sC2[RPB], sBs[RPB], sSp[RPB];
    __shared__ int   redrow[RPB];
    __shared__ int   sNr;
    __shared__ float sNll[RPB];

    float* xA   = bigA;            // [16][900]  P1 input (gather)
    float* rA   = bigA;            // [16][600]  P2b input (compacted, 2-phase copy)
    float* sR   = bigA + 9600;     // [16][216]  P3 r-gate exchange
    float* thN  = bigA + 13056;    // [16][64]   P3 th_new (compacted)
    float* gAb  = bigA;            // slice0: [16][320]
    float* gOut = bigA + 5120;     // slice0: [16][256]

    const int tid = threadIdx.x;
    const int bid = blockIdx.x;
    const int sl  = bid >> 5;          // slice 0..7 (same rg -> same XCD slot)
    const int rg  = bid & 31;
    const int b0  = rg * RPB;
    cg::grid_group grid = cg::this_grid();

    const int CNT   = (sl == 7) ? 42 : 43;
    const int tbase = 43 * (sl - 1);

    for (int i = tid; i < RPB*TS; i += NTHR) { ((float*)sTh)[i] = 0.f; ((float*)sTc)[i] = 0.f; }
    if (tid < RPB) sNll[tid] = 0.f;
    if (tid < 432) {
        int c = tid % 216;
        int g = -1;
        if (sl >= 1 && c < 5*CNT) g = (c/CNT)*300 + tbase + (c % CNT);
        vtab[tid] = g;
    }
    __syncthreads();

    auto GATHER = [&](int t){
        if (tid < RPB) {
            int b = b0 + tid;
            sC1[tid] = src1[t*B_ + b];
            sC2[tid] = src2[t*B_ + b];
            sBs[tid] = bsrcA[t*B_ + b];
            sSp[tid] = sspA[t*B_ + b];
        }
        __syncthreads();
        for (int f4 = tid; f4 < RPB*225; f4 += NTHR) {
            int r = f4/225, part = f4 - r*225;
            int b = b0 + r;
            float4 v = make_float4(0.f,0.f,0.f,0.f);
            int dst;
            if (part < 75) {
                int k = part*4; dst = r*900 + k;
                v = *(const float4*)&tokens[((size_t)b*NS + sBs[r])*600 + k];
            } else if (part < 150) {
                int k = (part-75)*4; dst = r*900 + 300 + k;
                int c = sC1[r];
                if (c >= 0)       v = *(const float4*)&tokens[((size_t)b*NS + c)*600 + k];
                else if (c <= -2) v = *(const float4*)&stack [((size_t)b*NS + (-c-2))*600 + k];
            } else {
                int k = (part-150)*4; dst = r*900 + 600 + k;
                int c = sC2[r];
                if (c >= 0)       v = *(const float4*)&tokens[((size_t)b*NS + c)*600 + k];
                else if (c <= -2) v = *(const float4*)&stack [((size_t)b*NS + (-c-2))*600 + k];
            }
            *(float4*)&xA[dst] = v;
        }
        __syncthreads();
    };

    GATHER(0);

    for (int t = 0; t < TT; ++t) {
        float racc[2][8];
        #pragma unroll
        for (int i = 0; i < 8; ++i) { racc[0][i] = 0.f; racc[1][i] = 0.f; }

        // =============== P1: x = [bh|s1h|s2h] @ [Wb;Ws1;Ws2] ================
        {
            const int xks = tid & 3;            // k-split (windows 240/240/240/180)
            const int xq  = (tid >> 2) & 3;     // row quad
            const int xc  = tid >> 4;           // 0..31
            const int wb  = xks * 240;
            const int wlen = (xks < 3) ? 240 : 180;
            float acc[4] = {0.f,0.f,0.f,0.f};
            float4 sreg[2];
            auto loadX = [&](int p){
                #pragma unroll
                for (int i = 0; i < 2; ++i) {
                    int f4 = tid + i*NTHR;
                    float v[4] = {0.f,0.f,0.f,0.f};
                    if (f4 < 640) {
                        int kk = f4 >> 5, vq = f4 & 31;
                        #pragma unroll
                        for (int e = 0; e < 4; ++e) {
                            int vcol = vq*4 + e;
                            int ks = vcol >> 5, cl = vcol & 31;
                            int off = p*20 + kk;
                            int len = (ks < 3) ? 240 : 180;
                            if (off < len) {
                                int kg = ks*240 + off;
                                float w;
                                if (kg < 300)      w = Wb [kg*G4 + sl*32 + cl];
                                else if (kg < 600) w = Ws1[(kg-300)*G4 + sl*32 + cl];
                                else               w = Ws2[(kg-600)*G4 + sl*32 + cl];
                                v[e] = w;
                            }
                        }
                    }
                    sreg[i] = make_float4(v[0],v[1],v[2],v[3]);
                }
            };
            auto writeX = [&](int p){
                #pragma unroll
                for (int i = 0; i < 2; ++i) {
                    int f4 = tid + i*NTHR;
                    if (f4 < 640) {
                        int kk = f4 >> 5, vq = f4 & 31;
                        *(float4*)&panelBuf[(p&1)*PANSZ + kk*128 + vq*4] = sreg[i];
                    }
                }
            };
            loadX(0); writeX(0); __syncthreads();
            for (int p = 0; p < 12; ++p) {
                if (p+1 < 12) loadX(p+1);
                if (p*20 < wlen) {
                    const float* pan = &panelBuf[(p&1)*PANSZ];
                    const int vcol = xks*32 + xc;
                    const int kb = wb + p*20;
                    #pragma unroll
                    for (int j = 0; j < 5; ++j) {
                        float w0 = pan[(4*j+0)*128 + vcol];
                        float w1 = pan[(4*j+1)*128 + vcol];
                        float w2 = pan[(4*j+2)*128 + vcol];
                        float w3 = pan[(4*j+3)*128 + vcol];
                        #pragma unroll
                        for (int rr = 0; rr < 4; ++rr) {
                            float4 a = *(const float4*)&xA[(xq*4+rr)*900 + kb + 4*j];
                            acc[rr] += a.x*w0 + a.y*w1 + a.z*w2 + a.w*w3;
                        }
                    }
                }
                if (p+1 < 12) writeX(p+1);
                __syncthreads();
            }
            #pragma unroll
            for (int rr = 0; rr < 4; ++rr) {
                acc[rr] += __shfl_xor(acc[rr], 1, 64);
                acc[rr] += __shfl_xor(acc[rr], 2, 64);
            }
            if (xks == 0) {
                #pragma unroll
                for (int rr = 0; rr < 4; ++rr)
                    xBuf[(size_t)(b0 + xq*4 + rr)*G4 + sl*32 + xc] = acc[rr];
            }
        }

        grid.sync();   // ---- sync 1: xBuf ready ----

        if (sl == 0) {
            // ============ P2a: g-GEMM + tracking LSTM + logits/nll ==========
            for (int f4 = tid; f4 < RPB*80; f4 += NTHR) {
                int r = f4/80, q = f4 - r*80, k4 = q*4;
                float4 v;
                if (k4 < 256) v = *(const float4*)&xBuf[(size_t)(b0+r)*G4 + k4];
                else          v = *(const float4*)&sTh[r][k4-256];
                *(float4*)&gAb[r*320 + k4] = v;
            }
            __syncthreads();
            const int gks = tid & 1, gcp = (tid >> 1) & 127, goct = tid >> 8;
            const int c0 = gcp*2;
            float acc[2][8];
            #pragma unroll
            for (int i = 0; i < 8; ++i) { acc[0][i] = 0.f; acc[1][i] = 0.f; }
            float4 sreg[4];
            auto loadG = [&](int p){
                #pragma unroll
                for (int i = 0; i < 4; ++i) {
                    int f4 = tid + i*NTHR;   // < 2048
                    int kk = f4 >> 7, vq = f4 & 127;
                    float v[4];
                    #pragma unroll
                    for (int e = 0; e < 4; ++e) {
                        int vcol = vq*4 + e;
                        int ks = vcol >> 8, cl = vcol & 255;
                        int kg = ks*160 + p*16 + kk;
                        v[e] = (kg < 256) ? W_ih[kg*G4 + cl] : W_hh[(kg-256)*G4 + cl];
                    }
                    sreg[i] = make_float4(v[0],v[1],v[2],v[3]);
                }
            };
            auto writeG = [&](int p){
                #pragma unroll
                for (int i = 0; i < 4; ++i) {
                    int f4 = tid + i*NTHR;
                    int kk = f4 >> 7, vq = f4 & 127;
                    *(float4*)&panelBuf[(p&1)*PANSZ + kk*512 + vq*4] = sreg[i];
                }
            };
            loadG(0); writeG(0); __syncthreads();
            for (int p = 0; p < 10; ++p) {
                if (p+1 < 10) loadG(p+1);
                {
                    const float* pan = &panelBuf[(p&1)*PANSZ];
                    const int kb = gks*160 + p*16;
                    #pragma unroll
                    for (int j = 0; j < 4; ++j) {
                        float2 w0 = *(const float2*)&pan[(4*j+0)*512 + gks*256 + c0];
                        float2 w1 = *(const float2*)&pan[(4*j+1)*512 + gks*256 + c0];
                        float2 w2 = *(const float2*)&pan[(4*j+2)*512 + gks*256 + c0];
                        float2 w3 = *(const float2*)&pan[(4*j+3)*512 + gks*256 + c0];
                        #pragma unroll
                        for (int row = 0; row < 8; ++row) {
                            float4 a = *(const float4*)&gAb[(goct*8+row)*320 + kb + 4*j];
                            acc[0][row] += a.x*w0.x + a.y*w1.x + a.z*w2.x + a.w*w3.x;
                            acc[1][row] += a.x*w0.y + a.y*w1.y + a.z*w2.y + a.w*w3.y;
                        }
                    }
                }
                if (p+1 < 10) writeG(p+1);
                __syncthreads();
            }
            #pragma unroll
            for (int row = 0; row < 8; ++row) {
                acc[0][row] += __shfl_xor(acc[0][row], 1, 64);
                acc[1][row] += __shfl_xor(acc[1][row], 1, 64);
            }
            if (gks == 0) {
                #pragma unroll
                for (int row = 0; row < 8; ++row) {
                    gOut[(goct*8+row)*256 + c0]     = acc[0][row];
                    gOut[(goct*8+row)*256 + c0 + 1] = acc[1][row];
                }
            }
            __syncthreads();
            #pragma unroll
            for (int pass = 0; pass < 2; ++pass) {
                int r = (tid >> 6) + pass*8, k = tid & 63;
                float gi = gOut[r*256 + k],       gf = gOut[r*256 + 64 + k];
                float gg = gOut[r*256 + 128 + k], go = gOut[r*256 + 192 + k];
                float tcn = sigf(gf)*sTc[r][k] + sigf(gi)*tanhf(gg);
                float thn = sigf(go)*tanhf(tcn);
                sTc[r][k] = tcn; sTh[r][k] = thn;
                thBuf[(size_t)(b0+r)*TS + k] = thn;
                float p0 = thn * Wt[2*k], p1 = thn * Wt[2*k+1];
                #pragma unroll
                for (int o = 32; o > 0; o >>= 1) {
                    p0 += __shfl_xor(p0, o, 64);
                    p1 += __shfl_xor(p1, o, 64);
                }
                if (k == 0) {
                    float l0 = p0 + bt[0], l1 = p1 + bt[1];
                    float m = fmaxf(l0, l1);
                    float lse = m + logf(expf(l0-m) + expf(l1-m));
                    int tr = trans[(size_t)(b0+r)*TT + t];
                    sNll[r] += lse - (tr ? l1 : l0);
                }
            }
        } else {
            // ============ P2b: r s-part = s2h@WL + s1h@WR (reduce rows) =====
            if (tid == 0) {
                int n = 0;
                for (int r = 0; r < RPB; ++r)
                    if (trans[(size_t)(b0+r)*TT + t]) redrow[n++] = r;
                sNr = n;
            }
            __syncthreads();
            const int nr = sNr;
            if (nr > 0) {
                // compact copy xA -> rA (read-all / sync / write-all)
                float4 creg[5];
                #pragma unroll
                for (int i = 0; i < 5; ++i) {
                    int f4 = tid + i*NTHR;
                    float4 v = make_float4(0.f,0.f,0.f,0.f);
                    if (f4 < 2400) {
                        int j = f4/150, q = f4 - j*150, k4 = q*4;
                        if (j < nr) {
                            int srow = redrow[j];
                            int off = (k4 < 300) ? (600 + k4) : k4;  // s2h | s1h
                            v = *(const float4*)&xA[srow*900 + off];
                        }
                    }
                    creg[i] = v;
                }
                __syncthreads();
                #pragma unroll
                for (int i = 0; i < 5; ++i) {
                    int f4 = tid + i*NTHR;
                    if (f4 < 2400) *(float4*)&rA[f4*4] = creg[i];
                }
                __syncthreads();
                const int cp  = tid % 108;
                const int rs  = (tid / 108) & 1;
                const int oct = tid / 216;
                const bool act = (tid < 432);
                const int cA = cp*2, cB = cp*2 + 1;
                const bool doOct = act && (oct == 0 || nr > 8);
                float4 sreg[5];
                auto loadR = [&](int p){
                    #pragma unroll
                    for (int i = 0; i < 5; ++i) {
                        int f4 = tid + i*NTHR;
                        float v[4] = {0.f,0.f,0.f,0.f};
                        if (f4 < 2160) {
                            int kk = f4/108, vq = f4 - kk*108;
                            #pragma unroll
                            for (int e = 0; e < 4; ++e) {
                                int vc = vq*4 + e;
                                int s = vc >= 216;
                                int c = vc - s*216;
                                int g = vtab[c];
                                if (g >= 0)
                                    v[e] = (s ? WR : WL)[(size_t)(p*20+kk)*R5 + g];
                            }
                        }
                        sreg[i] = make_float4(v[0],v[1],v[2],v[3]);
                    }
                };
                auto writeR = [&](int p){
                    #pragma unroll
                    for (int i = 0; i < 5; ++i) {
                        int f4 = tid + i*NTHR;
                        if (f4 < 2160) {
                            int kk = f4/108, vq = f4 - kk*108;
                            *(float4*)&panelBuf[(p&1)*PANSZ + kk*432 + vq*4] = sreg[i];
                        }
                    }
                };
                loadR(0); writeR(0); __syncthreads();
                for (int p = 0; p < 15; ++p) {
                    if (p+1 < 15) loadR(p+1);
                    if (doOct) {
                        const float* pan = &panelBuf[(p&1)*PANSZ];
                        const int kb = rs*300 + p*20;
                        #pragma unroll
                        for (int j = 0; j < 5; ++j) {
                            float2 w0 = *(const float2*)&pan[(4*j+0)*432 + rs*216 + cA];
                            float2 w1 = *(const float2*)&pan[(4*j+1)*432 + rs*216 + cA];
                            float2 w2 = *(const float2*)&pan[(4*j+2)*432 + rs*216 + cA];
                            float2 w3 = *(const float2*)&pan[(4*j+3)*432 + rs*216 + cA];
                            #pragma unroll
                            for (int row = 0; row < 8; ++row) {
                                float4 a = *(const float4*)&rA[(oct*8+row)*600 + kb + 4*j];
                                racc[0][row] += a.x*w0.x + a.y*w1.x + a.z*w2.x + a.w*w3.x;
                                racc[1][row] += a.x*w0.y + a.y*w1.y + a.z*w2.y + a.w*w3.y;
                            }
                        }
                    }
                    if (p+1 < 15) writeR(p+1);
                    __syncthreads();
                }
            }
        }

        grid.sync();   // ---- sync 2: thBuf ready ----

        // =============== P3: r += th_new@Wtr, tree LSTM, stack write ========
        if (sl >= 1) {
            const int nr = sNr;
            if (nr > 0) {
                for (int f4 = tid; f4 < nr*16; f4 += NTHR) {
                    int j = f4 >> 4, q = f4 & 15;
                    *(float4*)&thN[j*64 + q*4] =
                        *(const float4*)&thBuf[(size_t)(b0+redrow[j])*TS + q*4];
                }
                __syncthreads();
                const int cp  = tid % 108;
                const int rs  = (tid / 108) & 1;
                const int oct = tid / 216;
                const bool act = (tid < 432);
                const int cA = cp*2, cB = cp*2 + 1;
                const int gc0 = act ? vtab[cA] : -1;
                const int gc1 = act ? vtab[cB] : -1;
                const bool doOct = act && (oct == 0 || nr > 8);
                if (doOct && gc0 >= 0) {
                    #pragma unroll
                    for (int kk4 = 0; kk4 < 8; ++kk4) {
                        int k = rs*32 + kk4*4;
                        float wa0 = Wtr[(size_t)(k+0)*R5 + gc0];
                        float wa1 = Wtr[(size_t)(k+1)*R5 + gc0];
                        float wa2 = Wtr[(size_t)(k+2)*R5 + gc0];
                        float wa3 = Wtr[(size_t)(k+3)*R5 + gc0];
                        float wb0=0.f, wb1=0.f, wb2=0.f, wb3=0.f;
                        if (gc1 >= 0) {
                            wb0 = Wtr[(size_t)(k+0)*R5 + gc1];
                            wb1 = Wtr[(size_t)(k+1)*R5 + gc1];
                            wb2 = Wtr[(size_t)(k+2)*R5 + gc1];
                            wb3 = Wtr[(size_t)(k+3)*R5 + gc1];
                        }
                        #pragma unroll
                        for (int row = 0; row < 8; ++row) {
                            float4 a = *(const float4*)&thN[(oct*8+row)*64 + k];
                            racc[0][row] += a.x*wa0 + a.y*wa1 + a.z*wa2 + a.w*wa3;
                            racc[1][row] += a.x*wb0 + a.y*wb1 + a.z*wb2 + a.w*wb3;
                        }
                    }
                }
                if (doOct && rs == 0) {
                    #pragma unroll
                    for (int row = 0; row < 8; ++row) {
                        int rw = oct*8 + row;
                        if (gc0 >= 0) sR[rw*216 + cA] = racc[0][row];
                        if (gc1 >= 0) sR[rw*216 + cB] = racc[1][row];
                    }
                }
                __syncthreads();
                if (doOct && rs == 1) {
                    #pragma unroll
                    for (int row = 0; row < 8; ++row) {
                        int rw = oct*8 + row;
                        if (gc0 >= 0) sR[rw*216 + cA] += racc[0][row] + bL[gc0];
                        if (gc1 >= 0) sR[rw*216 + cB] += racc[1][row] + bL[gc1];
                    }
                }
                __syncthreads();
                for (int idx = tid; idx < nr*CNT; idx += NTHR) {
                    int j = idx / CNT, tcl = idx - j*CNT;
                    int rr = redrow[j];
                    int b = b0 + rr;
                    int tcg = tbase + tcl;
                    float ra  = sR[j*216 + 0*CNT + tcl];
                    float ri  = sR[j*216 + 1*CNT + tcl];
                    float rf1 = sR[j*216 + 2*CNT + tcl];
                    float rf2 = sR[j*216 + 3*CNT + tcl];
                    float ro  = sR[j*216 + 4*CNT + tcl];
                    int c1 = sC1[rr], c2 = sC2[rr];
                    float s1c = (c1 >= 0) ? tokens[((size_t)b*NS + c1)*600 + 300 + tcg]
                                          : stack [((size_t)b*NS + (-c1-2))*600 + 300 + tcg];
                    float s2c = (c2 >= 0) ? tokens[((size_t)b*NS + c2)*600 + 300 + tcg]
                                          : stack [((size_t)b*NS + (-c2-2))*600 + 300 + tcg];
                    float rcv = tanhf(ra)*sigf(ri) + sigf(rf1)*s2c + sigf(rf2)*s1c;
                    float rhv = sigf(ro)*tanhf(rcv);
                    int slot = sSp[rr] - 2;
                    stack[((size_t)b*NS + slot)*600 + tcg]       = rhv;
                    stack[((size_t)b*NS + slot)*600 + 300 + tcg] = rcv;
                }
            }
        }

        grid.sync();   // ---- sync 3: stack ready ----

        if (t + 1 < TT) GATHER(t + 1);
    }

    // ---------------- epilogue: final items + per-row nll -------------------
    if (sl == 0) {
        if (tid < RPB) nllBuf[b0 + tid] = sNll[tid];
        for (int f4 = tid; f4 < RPB*150; f4 += NTHR) {
            int r = f4/150, k4 = (f4 - r*150)*4;
            int b = b0 + r;
            int c = finCode[b];
            float4 v = make_float4(0.f,0.f,0.f,0.f);
            if (c >= 0)       v = *(const float4*)&tokens[((size_t)b*NS + c)*600 + k4];
            else if (c <= -2) v = *(const float4*)&stack [((size_t)b*NS + (-c-2))*600 + k4];
            *(float4*)&out[(size_t)b*600 + k4] = v;
        }
    }
}

__global__ void kNll(const float* __restrict__ nllBuf, float* __restrict__ out)
{
    __shared__ float sb[512];
    int tid = threadIdx.x;
    sb[tid] = nllBuf[tid];
    __syncthreads();
    for (int s = 256; s > 0; s >>= 1) {
        if (tid < s) sb[tid] += sb[tid + s];
        __syncthreads();
    }
    if (tid == 0) out[(size_t)B_*600] = sb[0] / (float)(TT * B_);
}

// ---------------------------------------------------------------------------
extern "C" void kernel_launch(void* const* d_in, const int* in_sizes, int n_in,
                              void* d_out, int out_size, void* d_ws, size_t ws_size,
                              hipStream_t stream)
{
    (void)in_sizes; (void)n_in; (void)out_size; (void)ws_size;
    const float* tokens = (const float*)d_in[0];
    const float* Wb   = (const float*)d_in[1];
    const float* Ws1  = (const float*)d_in[2];
    const float* Ws2  = (const float*)d_in[3];
    const float* W_ih = (const float*)d_in[4];
    const float* W_hh = (const float*)d_in[5];
    const float* Wt   = (const float*)d_in[6];
    const float* bt   = (const float*)d_in[7];
    const float* WL   = (const float*)d_in[8];
    const float* WR   = (const float*)d_in[9];
    const float* Wtr  = (const float*)d_in[10];
    const float* bL   = (const float*)d_in[11];
    const int* trans  = (const int*)d_in[12];
    float* out = (float*)d_out;

    char* p = (char*)d_ws;
    float* stack  = (float*)p;  p += (size_t)B_ * NS * 600 * 4;   // 157,286,400
    float* xBuf   = (float*)p;  p += (size_t)B_ * G4 * 4;         //     524,288
    float* thBuf  = (float*)p;  p += (size_t)B_ * TS * 4;         //     131,072
    float* nllBuf = (float*)p;  p += (size_t)B_ * 4;              //       2,048
    int* src1     = (int*)p;    p += (size_t)TT * B_ * 4;         //     522,240
    int* src2     = (int*)p;    p += (size_t)TT * B_ * 4;
    int* bsrcA    = (int*)p;    p += (size_t)TT * B_ * 4;
    int* sspA     = (int*)p;    p += (size_t)TT * B_ * 4;
    int* finCode  = (int*)p;    p += (size_t)B_ * 4;

    kSched<<<2, 256, 0, stream>>>(trans, src1, src2, bsrcA, sspA, finCode);

    void* args[] = { (void*)&tokens, (void*)&Wb, (void*)&Ws1, (void*)&Ws2,
                     (void*)&W_ih, (void*)&W_hh, (void*)&Wt, (void*)&bt,
                     (void*)&WL, (void*)&WR, (void*)&Wtr, (void*)&bL,
                     (void*)&trans, (void*)&src1, (void*)&src2, (void*)&bsrcA,
                     (void*)&sspA, (void*)&finCode, (void*)&stack, (void*)&xBuf,
                     (void*)&thBuf, (void*)&nllBuf, (void*)&out };
    hipLaunchCooperativeKernel((void*)kSpinn, dim3(NBLK), dim3(NTHR), args, 0, stream);

    kNll<<<1, 512, 0, stream>>>(nllBuf, out);
}